// Round 5
// baseline (775.372 us; speedup 1.0000x reference)
//
#include <hip/hip_runtime.h>
#include <hip/hip_bf16.h>
#include <stdint.h>

#define N_NODES 500000
#define N_EDGES 600000
#define N_GRAPHS 4096
#define XD 128
#define HD 128
#define ZD 64
#define BROWS 64                 // nodes per bucket
#define NBUCKETS 7813            // ceil(N_NODES/64)
#define CAP 160                  // bucket capacity (lambda=76.8)

// float-offsets in ws
#define OFF_CUR   0ull           // 8192 ints
#define OFF_SUMS  8192ull        // 524288 f
#define OFF_BUF   532480ull      // uint2 x NBUCKETS*CAP
#define OFF_CNT   3032640ull     // 4096 f
#define OFF_AT    3036736ull     // 524288 f
#define OFF_STATS 3561024ull     // 256 f
#define OFF_WT    3561280ull     // 16384 u32 (bf16 panels: [0]=Wnbr, [8192]=Wself)
#define OFF_U     3577664ull     // 32,000,000 u32: U = bf16(x @ Wnbr), [N][64 u32]

typedef __attribute__((ext_vector_type(8))) short bf16x8;
typedef __attribute__((ext_vector_type(4))) float f32x4;

__device__ inline uint32_t pk_bf16(float lo, float hi) {
  uint32_t ul = __float_as_uint(lo); ul += 0x7fffu + ((ul >> 16) & 1u);
  uint32_t uh = __float_as_uint(hi); uh += 0x7fffu + ((uh >> 16) & 1u);
  return (ul >> 16) | (uh & 0xffff0000u);
}

// acc layout: logical (row,col) -> f32 index row*128 + (((col&3)<<5)|(col>>2)) ^ (((row>>2)&7)<<2)
__device__ inline int accidx(int row, int col) {
  return row * 128 + (((((col & 3) << 5) | (col >> 2))) ^ (((row >> 2) & 7) << 2));
}

// ---------------- K0: preconvert W to bf16 panels, [n][k2] layout ----------------
__global__ void wprep_kernel(const float* __restrict__ Wnbr, const float* __restrict__ Wself,
                             uint32_t* __restrict__ wt) {
  const float* __restrict__ W = blockIdx.x ? Wself : Wnbr;
  uint32_t* __restrict__ out = wt + (size_t)blockIdx.x * 8192;
  const int t = threadIdx.x;          // 256
  const int n = t >> 1, h = t & 1;
  for (int q = 0; q < 32; ++q) {
    int k2 = h * 32 + q;
    float lo = W[(2 * k2) * HD + n];
    float hi = W[(2 * k2 + 1) * HD + n];
    out[n * 64 + k2] = pk_bf16(lo, hi);
  }
}

// ---------------- K1: bucket edges by dst>>6 ----------------
__global__ void bucket_build(const int* __restrict__ ei, const float* __restrict__ ew,
                             int* __restrict__ cursors, uint2* __restrict__ buf) {
  int e = blockIdx.x * blockDim.x + threadIdx.x;
  if (e >= N_EDGES) return;
  int src = ei[e];
  int dst = ei[N_EDGES + e];
  float w = ew[e];
  int b = dst >> 6;
  int slot = atomicAdd(cursors + b, 1);
  if (slot < CAP)
    buf[(size_t)b * CAP + slot] =
        make_uint2(((uint32_t)src << 6) | (uint32_t)(dst & 63), __float_as_uint(w));
}

// ---------------- counts via binary search on sorted batch ----------------
__global__ void counts_kernel(const int* __restrict__ batch, float* __restrict__ counts) {
  int g = blockIdx.x * blockDim.x + threadIdx.x;
  if (g >= N_GRAPHS) return;
  int lo = 0, hi = N_NODES;
  while (lo < hi) { int mid = (lo + hi) >> 1; if (batch[mid] < g) lo = mid + 1; else hi = mid; }
  int s = lo; hi = N_NODES;
  while (lo < hi) { int mid = (lo + hi) >> 1; if (batch[mid] < g + 1) lo = mid + 1; else hi = mid; }
  counts[g] = (float)(lo - s);
}

// ---------------- K_gemm1: U = bf16(x @ Wnbr), 64-row tiles ----------------
__launch_bounds__(512, 8)
__global__ void gemm1_u(const float* __restrict__ x, const uint32_t* __restrict__ wt,
                        uint32_t* __restrict__ U) {
  __shared__ char lb[32768];   // [0,16K) A bf16 swizzled; [16K,32K) C bf16 swizzled
  const int b = blockIdx.x;
  const int tid = threadIdx.x;
  const int node0 = b * BROWS;
  const int l = tid & 63, w = tid >> 6;
  const int wm = w >> 2, wn = w & 3;
  const int lr = l & 15, lk = l >> 4;

  // stage A-tile = x rows bf16, 16B slot s at (s ^ (row&7))
  {
    const int row = tid >> 3, c8 = tid & 7;
    int m = node0 + row;
    int mc = m < N_NODES ? m : N_NODES - 1;
    const float* xr = x + (size_t)mc * XD + c8 * 16;
    uint32_t p[8];
#pragma unroll
    for (int i = 0; i < 4; ++i) {
      float4 t4 = *(const float4*)(xr + i * 4);
      p[2 * i]     = pk_bf16(t4.x, t4.y);
      p[2 * i + 1] = pk_bf16(t4.z, t4.w);
    }
    char* aw = lb + row * 256;
    const int s0 = c8 * 2;
    *(uint4*)(aw + (((s0)     ^ (row & 7)) << 4)) = make_uint4(p[0], p[1], p[2], p[3]);
    *(uint4*)(aw + (((s0 + 1) ^ (row & 7)) << 4)) = make_uint4(p[4], p[5], p[6], p[7]);
  }
  __syncthreads();

  f32x4 acc[2][2];
#pragma unroll
  for (int mf = 0; mf < 2; ++mf) { acc[mf][0] = (f32x4)0.f; acc[mf][1] = (f32x4)0.f; }

  {
    const char* wtb = (const char*)wt;   // panel 0 = Wnbr
    bf16x8 bf[4][2];
#pragma unroll
    for (int kb = 0; kb < 4; ++kb)
#pragma unroll
      for (int nf = 0; nf < 2; ++nf) {
        int n = wn * 32 + nf * 16 + lr;
        bf[kb][nf] = *(const bf16x8*)(wtb + n * 256 + (kb << 6) + (lk << 4));
      }
#pragma unroll
    for (int kb = 0; kb < 4; ++kb) {
      int slot = (kb << 2) | lk;
#pragma unroll
      for (int mf = 0; mf < 2; ++mf) {
        int r = wm * 32 + mf * 16 + lr;
        bf16x8 a = *(const bf16x8*)(lb + r * 256 + ((slot ^ (r & 7)) << 4));
        acc[mf][0] = __builtin_amdgcn_mfma_f32_16x16x32_bf16(a, bf[kb][0], acc[mf][0], 0, 0, 0);
        acc[mf][1] = __builtin_amdgcn_mfma_f32_16x16x32_bf16(a, bf[kb][1], acc[mf][1], 0, 0, 0);
      }
    }
  }
  __syncthreads();  // A reads done

  // C -> LDS bf16, byte-within-row swizzled by ((row&7)<<4)
  {
#pragma unroll
    for (int mf = 0; mf < 2; ++mf)
#pragma unroll
      for (int nf = 0; nf < 2; ++nf) {
        int col = wn * 32 + nf * 16 + lr;
#pragma unroll
        for (int r = 0; r < 4; ++r) {
          int row = wm * 32 + mf * 16 + lk * 4 + r;
          uint32_t uv = __float_as_uint(acc[mf][nf][r]);
          uv += 0x7fffu + ((uv >> 16) & 1u);
          *(unsigned short*)(lb + 16384 + row * 256 + ((col * 2) ^ ((row & 7) << 4))) =
              (unsigned short)(uv >> 16);
        }
      }
  }
  __syncthreads();

  // coalesced store out (32B per thread)
  {
    const int row = tid >> 3, seg = tid & 7;
    const char* cr = lb + 16384 + row * 256;
    const int swz = (row & 7) << 4;
    uint4 v0 = *(const uint4*)(cr + ((seg * 32) ^ swz));
    uint4 v1 = *(const uint4*)(cr + ((seg * 32 + 16) ^ swz));
    int m = node0 + row;
    int mc = m < N_NODES ? m : N_NODES - 1;
    char* dst = (char*)U + (size_t)mc * 256 + seg * 32;
    *(uint4*)(dst)      = v0;
    *(uint4*)(dst + 16) = v1;
  }
}

// ------- K_fused2: gather U -> LDS f32 acc (output space) + MFMA x@Wself + pool -------
// 48KB LDS: [0,32K) acc f32 [64][128] (perm layout) -> z in place; [32K,48K) A-tile bf16
__launch_bounds__(512, 6)
__global__ void embed_fused2(const float* __restrict__ x, const uint32_t* __restrict__ U,
                             const uint2* __restrict__ buf, const int* __restrict__ cursors,
                             const uint32_t* __restrict__ wt,
                             const float* __restrict__ bemb, const int* __restrict__ batch,
                             float* __restrict__ sums) {
  __shared__ float lds[12288];  // 48KB
  char* lb = (char*)lds;
  const int b = blockIdx.x;
  const int tid = threadIdx.x;
  const int node0 = b * BROWS;
  const int l = tid & 63, w = tid >> 6;
  const int wm = w >> 2, wn = w & 3;
  const int lr = l & 15, lk = l >> 4;

  // zero acc (32KB)
  {
    float4 z4 = make_float4(0.f, 0.f, 0.f, 0.f);
    float4* p = (float4*)lds;
    for (int i = tid; i < 2048; i += 512) p[i] = z4;
  }
  __syncthreads();

  // edge accumulation: gather U rows (256B bf16), conflict-free LDS atomics
  {
    int cnt = cursors[b]; if (cnt > CAP) cnt = CAP;
    const uint2* eb = buf + (size_t)b * CAP;
    const int eg = tid >> 5;      // 16 groups of 32 lanes
    const int c = tid & 31;       // lane covers logical cols 4c..4c+3
    int e = eg;
    if (e < cnt) {
      const int cl = cnt - 1;
      uint2 pkA = eb[e];
      int i1 = e + 16; if (i1 > cl) i1 = cl;
      uint2 pkB = eb[i1];
      uint2 uvA = *(const uint2*)(U + (size_t)(pkA.x >> 6) * 64 + c * 2);
      while (true) {
        int en = e + 16;
        int i2 = en + 16; if (i2 > cl) i2 = cl;
        uint2 pkC = eb[i2];
        uint2 uvB = *(const uint2*)(U + (size_t)(pkB.x >> 6) * 64 + c * 2);
        float wgt = __uint_as_float(pkA.y);
        int dloc = pkA.x & 63;
        int xr = ((dloc >> 2) & 7) << 2;
        float* ap = lds + dloc * 128 + (c ^ xr);
        atomicAdd(ap,      wgt * __uint_as_float(uvA.x << 16));
        atomicAdd(ap + 32, wgt * __uint_as_float(uvA.x & 0xffff0000u));
        atomicAdd(ap + 64, wgt * __uint_as_float(uvA.y << 16));
        atomicAdd(ap + 96, wgt * __uint_as_float(uvA.y & 0xffff0000u));
        e = en;
        if (e >= cnt) break;
        pkA = pkB; pkB = pkC; uvA = uvB;
      }
    }
  }

  // stage A-tile = x rows bf16 swizzled at [32K,48K)  (acc region untouched)
  __syncthreads();
  {
    const int row = tid >> 3, c8 = tid & 7;
    int m = node0 + row;
    int mc = m < N_NODES ? m : N_NODES - 1;
    const float* xr = x + (size_t)mc * XD + c8 * 16;
    uint32_t p[8];
#pragma unroll
    for (int i = 0; i < 4; ++i) {
      float4 t4 = *(const float4*)(xr + i * 4);
      p[2 * i]     = pk_bf16(t4.x, t4.y);
      p[2 * i + 1] = pk_bf16(t4.z, t4.w);
    }
    char* aw = lb + 32768 + row * 256;
    const int s0 = c8 * 2;
    *(uint4*)(aw + (((s0)     ^ (row & 7)) << 4)) = make_uint4(p[0], p[1], p[2], p[3]);
    *(uint4*)(aw + (((s0 + 1) ^ (row & 7)) << 4)) = make_uint4(p[4], p[5], p[6], p[7]);
  }
  __syncthreads();

  f32x4 acc[2][2];
#pragma unroll
  for (int mf = 0; mf < 2; ++mf) { acc[mf][0] = (f32x4)0.f; acc[mf][1] = (f32x4)0.f; }

  // MFMA: x @ Wself
  {
    const char* wtb = (const char*)wt + 32768;  // panel 1 = Wself
    bf16x8 bf[4][2];
#pragma unroll
    for (int kb = 0; kb < 4; ++kb)
#pragma unroll
      for (int nf = 0; nf < 2; ++nf) {
        int n = wn * 32 + nf * 16 + lr;
        bf[kb][nf] = *(const bf16x8*)(wtb + n * 256 + (kb << 6) + (lk << 4));
      }
#pragma unroll
    for (int kb = 0; kb < 4; ++kb) {
      int slot = (kb << 2) | lk;
#pragma unroll
      for (int mf = 0; mf < 2; ++mf) {
        int r = wm * 32 + mf * 16 + lr;
        bf16x8 a = *(const bf16x8*)(lb + 32768 + r * 256 + ((slot ^ (r & 7)) << 4));
        acc[mf][0] = __builtin_amdgcn_mfma_f32_16x16x32_bf16(a, bf[kb][0], acc[mf][0], 0, 0, 0);
        acc[mf][1] = __builtin_amdgcn_mfma_f32_16x16x32_bf16(a, bf[kb][1], acc[mf][1], 0, 0, 0);
      }
    }
  }

  // epilogue: z = relu(msg + x@Wself + bias), in place in acc region
  {
    float be0 = bemb[wn * 32 + lr];
    float be1 = bemb[wn * 32 + 16 + lr];
#pragma unroll
    for (int mf = 0; mf < 2; ++mf)
#pragma unroll
      for (int r = 0; r < 4; ++r) {
        int row = wm * 32 + mf * 16 + lk * 4 + r;
        int i0 = accidx(row, wn * 32 + lr);
        int i1 = accidx(row, wn * 32 + 16 + lr);
        lds[i0] = fmaxf(lds[i0] + acc[mf][0][r] + be0, 0.f);
        lds[i1] = fmaxf(lds[i1] + acc[mf][1][r] + be1, 0.f);
      }
  }
  __syncthreads();

  // segmented mean-pool: wave owns 8 consecutive sorted nodes (2 rows/thread)
  {
    const int mg = tid >> 4;
    const int n0 = (tid & 15) << 3;
    const int lane = tid & 63;
    float av[2][8];
    int bg[2];
#pragma unroll
    for (int i = 0; i < 2; ++i) {
      int row = mg * 2 + i;
      int m = node0 + row;
      int mc = m < N_NODES ? m : N_NODES - 1;
      bg[i] = (m < N_NODES) ? batch[mc] : 0x7fffffff;
#pragma unroll
      for (int j = 0; j < 8; ++j) av[i][j] = lds[accidx(row, n0 + j)];
    }
    int g = __shfl(bg[0], 0, 64);
    while (g != 0x7fffffff) {
      float s[8];
#pragma unroll
      for (int j = 0; j < 8; ++j) s[j] = 0.f;
#pragma unroll
      for (int i = 0; i < 2; ++i) {
        bool m = (bg[i] == g);
#pragma unroll
        for (int j = 0; j < 8; ++j) s[j] += m ? av[i][j] : 0.f;
      }
#pragma unroll
      for (int j = 0; j < 8; ++j) {
        s[j] += __shfl_xor(s[j], 16, 64);
        s[j] += __shfl_xor(s[j], 32, 64);
      }
      if (lane < 16) {
        float* sp = sums + (size_t)g * HD + n0;
#pragma unroll
        for (int j = 0; j < 8; ++j) atomicAdd(sp + j, s[j]);
      }
      int nb = 0x7fffffff;
#pragma unroll
      for (int i = 0; i < 2; ++i)
        if (bg[i] > g && bg[i] < nb) nb = bg[i];
      for (int off = 1; off < 64; off <<= 1) {
        int o = __shfl_xor(nb, off, 64);
        nb = o < nb ? o : nb;
      }
      g = nb;
    }
  }
}

// ---------------- K4: head linear ----------------
__global__ void head_kernel(const float* __restrict__ sums, const float* __restrict__ counts,
                            const float* __restrict__ y,
                            const float* __restrict__ Wmu, const float* __restrict__ bmu,
                            const float* __restrict__ Wvar, const float* __restrict__ bvar,
                            float* __restrict__ aT) {
  __shared__ float hrow[129];
  const int g = blockIdx.x;
  const int t = threadIdx.x;  // 128
  float cnt = fmaxf(counts[g], 1.f);
  hrow[t] = sums[(size_t)g * HD + t] / cnt;
  if (t == 0) hrow[128] = y[g];
  __syncthreads();
  const int head = t >> 6, n = t & 63;
  const float* __restrict__ W = head ? Wvar : Wmu;
  float acc = head ? bvar[n] : bmu[n];
  for (int k = 0; k < 129; ++k) acc = fmaf(hrow[k], W[k * ZD + n], acc);
  aT[(size_t)(head * ZD + n) * N_GRAPHS + g] = acc;
}

// ---------------- K5: BN stats per feature ----------------
__global__ void bnstats_kernel(const float* __restrict__ aT, float* __restrict__ stats) {
  const int f = blockIdx.x;  // 0..127
  const float* base = aT + (size_t)f * N_GRAPHS;
  float s = 0.f, ss = 0.f;
  for (int i = threadIdx.x; i < N_GRAPHS; i += 256) { float v = base[i]; s += v; ss += v * v; }
#pragma unroll
  for (int off = 1; off < 64; off <<= 1) { s += __shfl_xor(s, off, 64); ss += __shfl_xor(ss, off, 64); }
  __shared__ float ls[8];
  const int wav = threadIdx.x >> 6, lane = threadIdx.x & 63;
  if (lane == 0) { ls[wav * 2] = s; ls[wav * 2 + 1] = ss; }
  __syncthreads();
  if (threadIdx.x == 0) {
    float S = ls[0] + ls[2] + ls[4] + ls[6];
    float SS = ls[1] + ls[3] + ls[5] + ls[7];
    float mean = S / (float)N_GRAPHS;
    float var = SS / (float)N_GRAPHS - mean * mean;
    stats[f * 2] = mean;
    stats[f * 2 + 1] = rsqrtf(var + 1e-5f);
  }
}

// ---------------- K6: BN apply + relu (+sigmoid) ----------------
__global__ void bnapply_kernel(const float* __restrict__ aT, const float* __restrict__ stats,
                               const float* __restrict__ gm, const float* __restrict__ btm,
                               const float* __restrict__ gv, const float* __restrict__ btv,
                               float* __restrict__ out) {
  int t = blockIdx.x * blockDim.x + threadIdx.x;
  if (t >= 2 * N_GRAPHS * ZD) return;
  int head = t >> 18;
  int r = t & (N_GRAPHS * ZD - 1);
  int g = r >> 6, n = r & 63;
  int f = (head << 6) | n;
  float v = aT[(size_t)f * N_GRAPHS + g];
  float z = (v - stats[f * 2]) * stats[f * 2 + 1];
  z = z * (head ? gv[n] : gm[n]) + (head ? btv[n] : btm[n]);
  z = fmaxf(z, 0.f);
  if (head) z = 1.f / (1.f + __expf(-z));
  out[t] = z;
}

extern "C" void kernel_launch(void* const* d_in, const int* in_sizes, int n_in,
                              void* d_out, int out_size, void* d_ws, size_t ws_size,
                              hipStream_t stream) {
  const float* x      = (const float*)d_in[0];
  const int*   ei     = (const int*)d_in[1];
  const float* ew     = (const float*)d_in[2];
  const float* y      = (const float*)d_in[3];
  const int*   batch  = (const int*)d_in[4];
  const float* Wself  = (const float*)d_in[5];
  const float* Wnbr   = (const float*)d_in[6];
  const float* bemb   = (const float*)d_in[7];
  const float* Wmu    = (const float*)d_in[8];
  const float* bmu    = (const float*)d_in[9];
  const float* gmu    = (const float*)d_in[10];
  const float* betamu = (const float*)d_in[11];
  const float* Wvar   = (const float*)d_in[12];
  const float* bvar   = (const float*)d_in[13];
  const float* gvar   = (const float*)d_in[14];
  const float* betavar= (const float*)d_in[15];

  float* ws       = (float*)d_ws;
  int*   cursors  = (int*)(ws + OFF_CUR);
  float* sums     = ws + OFF_SUMS;
  uint2* buf      = (uint2*)(ws + OFF_BUF);
  float* counts   = ws + OFF_CNT;
  float* aT       = ws + OFF_AT;
  float* stats    = ws + OFF_STATS;
  uint32_t* wt    = (uint32_t*)(ws + OFF_WT);
  uint32_t* U     = (uint32_t*)(ws + OFF_U);

  // zero cursors + sums (~2.1MB, contiguous at ws base)
  hipMemsetAsync(ws, 0, (8192ull + 524288ull) * 4ull, stream);

  wprep_kernel<<<2, 256, 0, stream>>>(Wnbr, Wself, wt);
  bucket_build<<<(N_EDGES + 255) / 256, 256, 0, stream>>>(ei, ew, cursors, buf);
  counts_kernel<<<(N_GRAPHS + 255) / 256, 256, 0, stream>>>(batch, counts);
  gemm1_u<<<NBUCKETS, 512, 0, stream>>>(x, wt, U);
  embed_fused2<<<NBUCKETS, 512, 0, stream>>>(x, U, buf, cursors, wt, bemb, batch, sums);
  head_kernel<<<N_GRAPHS, 128, 0, stream>>>(sums, counts, y, Wmu, bmu, Wvar, bvar, aT);
  bnstats_kernel<<<128, 256, 0, stream>>>(aT, stats);
  bnapply_kernel<<<(2 * N_GRAPHS * ZD + 255) / 256, 256, 0, stream>>>(
      aT, stats, gmu, betamu, gvar, betavar, (float*)d_out);
}

// Round 6
// 736.696 us; speedup vs baseline: 1.0525x; 1.0525x over previous
//
#include <hip/hip_runtime.h>
#include <hip/hip_bf16.h>
#include <stdint.h>

#define N_NODES 500000
#define N_EDGES 600000
#define N_GRAPHS 4096
#define XD 128
#define HD 128
#define ZD 64
#define BROWS 64
#define NBUCKETS 7813            // ceil(N_NODES/64)
#define CAP 160                  // bucket capacity (lambda=76.8)

// float-offsets in ws
#define OFF_CUR    0ull          // 8192 ints
#define OFF_SUMS   8192ull       // 524288 f (fallback atomics only)
#define OFF_BUF    532480ull     // uint2 x NBUCKETS*CAP = 2500160 u32
#define OFF_AT     3032640ull    // 524288 f
#define OFF_STATS  3556928ull    // 256 f
#define OFF_WT     3557184ull    // 16384 u32 (bf16 panels: [0]=Wnbr, [8192]=Wself)
#define OFF_GMEAN  3573568ull    // 524288 f
#define OFF_PART   4097856ull    // NBUCKETS*8*128 = 8000512 f
#define OFF_U      12098368ull   // 32,000,000 u32: U = bf16(x@Wnbr)
#define OFF_V      44098368ull   // 32,000,000 u32: V = bf16(x@Wself + b)

typedef __attribute__((ext_vector_type(8))) short bf16x8;
typedef __attribute__((ext_vector_type(4))) float f32x4;

__device__ inline uint32_t pk_bf16(float lo, float hi) {
  uint32_t ul = __float_as_uint(lo); ul += 0x7fffu + ((ul >> 16) & 1u);
  uint32_t uh = __float_as_uint(hi); uh += 0x7fffu + ((uh >> 16) & 1u);
  return (ul >> 16) | (uh & 0xffff0000u);
}
__device__ inline float bl16(uint32_t u) { return __uint_as_float(u << 16); }
__device__ inline float bh16(uint32_t u) { return __uint_as_float(u & 0xffff0000u); }

// ---------------- K0: preconvert W to bf16 panels, [n][k2] layout ----------------
__global__ void wprep_kernel(const float* __restrict__ Wnbr, const float* __restrict__ Wself,
                             uint32_t* __restrict__ wt) {
  const float* __restrict__ W = blockIdx.x ? Wself : Wnbr;
  uint32_t* __restrict__ out = wt + (size_t)blockIdx.x * 8192;
  const int t = threadIdx.x;          // 256
  const int n = t >> 1, h = t & 1;
  for (int q = 0; q < 32; ++q) {
    int k2 = h * 32 + q;
    float lo = W[(2 * k2) * HD + n];
    float hi = W[(2 * k2 + 1) * HD + n];
    out[n * 64 + k2] = pk_bf16(lo, hi);
  }
}

// ---------------- K1: bucket edges by dst>>6 ----------------
__global__ void bucket_build(const int* __restrict__ ei, const float* __restrict__ ew,
                             int* __restrict__ cursors, uint2* __restrict__ buf) {
  int e = blockIdx.x * blockDim.x + threadIdx.x;
  if (e >= N_EDGES) return;
  int src = ei[e];
  int dst = ei[N_EDGES + e];
  float w = ew[e];
  int b = dst >> 6;
  int slot = atomicAdd(cursors + b, 1);
  if (slot < CAP)
    buf[(size_t)b * CAP + slot] =
        make_uint2(((uint32_t)src << 6) | (uint32_t)(dst & 63), __float_as_uint(w));
}

// ---------------- K2: U = bf16(x@Wnbr), V = bf16(x@Wself + bemb); one x pass --------
__launch_bounds__(512, 4)
__global__ void gemm1_uv(const float* __restrict__ x, const uint32_t* __restrict__ wt,
                         const float* __restrict__ bemb,
                         uint32_t* __restrict__ U, uint32_t* __restrict__ V) {
  __shared__ char lb[32768];   // [0,16K) A bf16 swizzled; [16K,32K) C bf16 swizzled
  const int b = blockIdx.x;
  const int tid = threadIdx.x;
  const int node0 = b * BROWS;
  const int l = tid & 63, w = tid >> 6;
  const int wm = w >> 2, wn = w & 3;
  const int lr = l & 15, lk = l >> 4;

  // stage A-tile = x rows bf16, 16B slot s at (s ^ (row&7))
  {
    const int row = tid >> 3, c8 = tid & 7;
    int m = node0 + row;
    int mc = m < N_NODES ? m : N_NODES - 1;
    const float* xr = x + (size_t)mc * XD + c8 * 16;
    uint32_t p[8];
#pragma unroll
    for (int i = 0; i < 4; ++i) {
      float4 t4 = *(const float4*)(xr + i * 4);
      p[2 * i]     = pk_bf16(t4.x, t4.y);
      p[2 * i + 1] = pk_bf16(t4.z, t4.w);
    }
    char* aw = lb + row * 256;
    const int s0 = c8 * 2;
    *(uint4*)(aw + (((s0)     ^ (row & 7)) << 4)) = make_uint4(p[0], p[1], p[2], p[3]);
    *(uint4*)(aw + (((s0 + 1) ^ (row & 7)) << 4)) = make_uint4(p[4], p[5], p[6], p[7]);
  }
  __syncthreads();

  f32x4 acc0[2][2], acc1[2][2];
#pragma unroll
  for (int mf = 0; mf < 2; ++mf) {
    acc0[mf][0] = (f32x4)0.f; acc0[mf][1] = (f32x4)0.f;
    acc1[mf][0] = (f32x4)0.f; acc1[mf][1] = (f32x4)0.f;
  }

  // panel 0 = Wnbr -> acc0
  {
    const char* wtb = (const char*)wt;
#pragma unroll
    for (int kb = 0; kb < 4; ++kb) {
      int slot = (kb << 2) | lk;
      bf16x8 bf0 = *(const bf16x8*)(wtb + (wn * 32 + lr) * 256 + (kb << 6) + (lk << 4));
      bf16x8 bf1 = *(const bf16x8*)(wtb + (wn * 32 + 16 + lr) * 256 + (kb << 6) + (lk << 4));
#pragma unroll
      for (int mf = 0; mf < 2; ++mf) {
        int r = wm * 32 + mf * 16 + lr;
        bf16x8 a = *(const bf16x8*)(lb + r * 256 + ((slot ^ (r & 7)) << 4));
        acc0[mf][0] = __builtin_amdgcn_mfma_f32_16x16x32_bf16(a, bf0, acc0[mf][0], 0, 0, 0);
        acc0[mf][1] = __builtin_amdgcn_mfma_f32_16x16x32_bf16(a, bf1, acc0[mf][1], 0, 0, 0);
      }
    }
  }
  // panel 1 = Wself -> acc1
  {
    const char* wtb = (const char*)wt + 32768;
#pragma unroll
    for (int kb = 0; kb < 4; ++kb) {
      int slot = (kb << 2) | lk;
      bf16x8 bf0 = *(const bf16x8*)(wtb + (wn * 32 + lr) * 256 + (kb << 6) + (lk << 4));
      bf16x8 bf1 = *(const bf16x8*)(wtb + (wn * 32 + 16 + lr) * 256 + (kb << 6) + (lk << 4));
#pragma unroll
      for (int mf = 0; mf < 2; ++mf) {
        int r = wm * 32 + mf * 16 + lr;
        bf16x8 a = *(const bf16x8*)(lb + r * 256 + ((slot ^ (r & 7)) << 4));
        acc1[mf][0] = __builtin_amdgcn_mfma_f32_16x16x32_bf16(a, bf0, acc1[mf][0], 0, 0, 0);
        acc1[mf][1] = __builtin_amdgcn_mfma_f32_16x16x32_bf16(a, bf1, acc1[mf][1], 0, 0, 0);
      }
    }
  }
  __syncthreads();

  // ---- U: acc0 -> C bf16 swizzled -> coalesced store ----
  {
#pragma unroll
    for (int mf = 0; mf < 2; ++mf)
#pragma unroll
      for (int nf = 0; nf < 2; ++nf) {
        int col = wn * 32 + nf * 16 + lr;
#pragma unroll
        for (int r = 0; r < 4; ++r) {
          int row = wm * 32 + mf * 16 + lk * 4 + r;
          uint32_t uv = __float_as_uint(acc0[mf][nf][r]);
          uv += 0x7fffu + ((uv >> 16) & 1u);
          *(unsigned short*)(lb + 16384 + row * 256 + ((col * 2) ^ ((row & 7) << 4))) =
              (unsigned short)(uv >> 16);
        }
      }
  }
  __syncthreads();
  {
    const int row = tid >> 3, seg = tid & 7;
    const char* cr = lb + 16384 + row * 256;
    const int swz = (row & 7) << 4;
    uint4 v0 = *(const uint4*)(cr + ((seg * 32) ^ swz));
    uint4 v1 = *(const uint4*)(cr + ((seg * 32 + 16) ^ swz));
    int m = node0 + row;
    int mc = m < N_NODES ? m : N_NODES - 1;
    char* dst = (char*)U + (size_t)mc * 256 + seg * 32;
    *(uint4*)(dst)      = v0;
    *(uint4*)(dst + 16) = v1;
  }
  __syncthreads();

  // ---- V: acc1 + bias -> C bf16 swizzled -> coalesced store ----
  {
    float be0 = bemb[wn * 32 + lr];
    float be1 = bemb[wn * 32 + 16 + lr];
#pragma unroll
    for (int mf = 0; mf < 2; ++mf)
#pragma unroll
      for (int nf = 0; nf < 2; ++nf) {
        int col = wn * 32 + nf * 16 + lr;
        float be = nf ? be1 : be0;
#pragma unroll
        for (int r = 0; r < 4; ++r) {
          int row = wm * 32 + mf * 16 + lk * 4 + r;
          uint32_t uv = __float_as_uint(acc1[mf][nf][r] + be);
          uv += 0x7fffu + ((uv >> 16) & 1u);
          *(unsigned short*)(lb + 16384 + row * 256 + ((col * 2) ^ ((row & 7) << 4))) =
              (unsigned short)(uv >> 16);
        }
      }
  }
  __syncthreads();
  {
    const int row = tid >> 3, seg = tid & 7;
    const char* cr = lb + 16384 + row * 256;
    const int swz = (row & 7) << 4;
    uint4 v0 = *(const uint4*)(cr + ((seg * 32) ^ swz));
    uint4 v1 = *(const uint4*)(cr + ((seg * 32 + 16) ^ swz));
    int m = node0 + row;
    int mc = m < N_NODES ? m : N_NODES - 1;
    char* dst = (char*)V + (size_t)mc * 256 + seg * 32;
    *(uint4*)(dst)      = v0;
    *(uint4*)(dst + 16) = v1;
  }
}

// ------- K3: gather U -> LDS f32 acc + z=relu(acc+V) + pool -> partials (no atomics) ----
// LDS 37.1KB: [0,8192) acc f32 [64][128] perm; [8192,9216) P[8][128]; [9216,9280) span
__launch_bounds__(512, 6)
__global__ void msg_pool(const uint32_t* __restrict__ U, const uint32_t* __restrict__ V,
                         const uint2* __restrict__ buf, const int* __restrict__ cursors,
                         const int* __restrict__ batch,
                         float* __restrict__ partials, float* __restrict__ sums) {
  __shared__ float lds[9280];
  int* span = (int*)(lds + 9216);
  const int b = blockIdx.x;
  const int tid = threadIdx.x;
  const int node0 = b * BROWS;

  // zero acc + P
  for (int i = tid; i < 9216; i += 512) lds[i] = 0.f;
  // span
  if (tid < BROWS) {
    int m = node0 + tid;
    span[tid] = (m < N_NODES) ? (batch[m] - batch[node0]) : -1;
  }
  __syncthreads();

  // edge accumulation: gather U rows (256B bf16), depth-3 pipeline, conflict-free atomics
  {
    int cnt = cursors[b]; if (cnt > CAP) cnt = CAP;
    const uint2* eb = buf + (size_t)b * CAP;
    const int eg = tid >> 5;      // 16 groups of 32 lanes
    const int c = tid & 31;       // lane covers logical cols 4c..4c+3
    int e = eg;
    if (e < cnt) {
      const int cl = cnt - 1;
      int i1 = e + 16; if (i1 > cl) i1 = cl;
      int i2 = e + 32; if (i2 > cl) i2 = cl;
      uint2 p0 = eb[e];
      uint2 p1 = eb[i1];
      uint2 p2 = eb[i2];
      uint2 u0 = *(const uint2*)(U + (size_t)(p0.x >> 6) * 64 + c * 2);
      uint2 u1 = *(const uint2*)(U + (size_t)(p1.x >> 6) * 64 + c * 2);
      while (true) {
        int i3 = e + 48; if (i3 > cl) i3 = cl;
        uint2 p3 = eb[i3];
        uint2 u2 = *(const uint2*)(U + (size_t)(p2.x >> 6) * 64 + c * 2);
        float wgt = __uint_as_float(p0.y);
        int dloc = p0.x & 63;
        int xr = ((dloc >> 2) & 7) << 2;
        float* ap = lds + dloc * 128 + (c ^ xr);
        atomicAdd(ap,      wgt * bl16(u0.x));
        atomicAdd(ap + 32, wgt * bh16(u0.x));
        atomicAdd(ap + 64, wgt * bl16(u0.y));
        atomicAdd(ap + 96, wgt * bh16(u0.y));
        e += 16;
        if (e >= cnt) break;
        p0 = p1; p1 = p2; p2 = p3; u0 = u1; u1 = u2;
      }
    }
  }
  __syncthreads();

  // epilogue: z = relu(acc + V), segmented pool into LDS P (streaming flush on sorted rows)
  {
    const int col = tid & 127;
    const int rg = tid >> 7;            // 4 rowgroups x 16 rows
    const int g_first = batch[node0];
    const int cperm = (col >> 2);
    const int coff = (col & 3) << 5;
    float pacc = 0.f;
    int jcur = -1;
#pragma unroll 4
    for (int r16 = 0; r16 < 16; ++r16) {
      int row = rg * 16 + r16;
      int j = span[row];
      if (j != jcur) {
        if (jcur >= 0) {
          if (jcur < 8) atomicAdd(&lds[8192 + jcur * 128 + col], pacc);
          else atomicAdd(&sums[(size_t)(g_first + jcur) * HD + col], pacc);
        }
        pacc = 0.f; jcur = j;
      }
      if (j >= 0) {
        int xr = ((row >> 2) & 7) << 2;
        float mv = lds[row * 128 + (cperm ^ xr) + coff];
        unsigned short vraw = *((const unsigned short*)V + (size_t)(node0 + row) * HD + col);
        float vv = __uint_as_float(((uint32_t)vraw) << 16);
        pacc += fmaxf(mv + vv, 0.f);
      }
    }
    if (jcur >= 0) {
      if (jcur < 8) atomicAdd(&lds[8192 + jcur * 128 + col], pacc);
      else atomicAdd(&sums[(size_t)(g_first + jcur) * HD + col], pacc);
    }
  }
  __syncthreads();

  // write P -> partials[b][8][128], coalesced
  {
    float2 v = *(float2*)&lds[8192 + tid * 2];
    *(float2*)(partials + (size_t)b * 1024 + tid * 2) = v;
  }
}

// ---------------- K4: per-graph reduction of partials -> mean ----------------
__global__ void reduce_mean(const float* __restrict__ partials, const float* __restrict__ sums,
                            const int* __restrict__ batch, float* __restrict__ gmean) {
  const int g = blockIdx.x;
  const int t = threadIdx.x;  // 128
  // node range of graph g
  int lo = 0, hi = N_NODES;
  while (lo < hi) { int mid = (lo + hi) >> 1; if (batch[mid] < g) lo = mid + 1; else hi = mid; }
  int s = lo; hi = N_NODES;
  while (lo < hi) { int mid = (lo + hi) >> 1; if (batch[mid] < g + 1) lo = mid + 1; else hi = mid; }
  int e = lo;
  float tot = sums[(size_t)g * HD + t];
  int cnt = e - s;
  if (cnt > 0) {
    int b0 = s >> 6, b1 = (e - 1) >> 6;
    for (int b = b0; b <= b1; ++b) {
      int j = g - batch[b * 64];
      if (j >= 0 && j < 8) tot += partials[(size_t)b * 1024 + j * 128 + t];
    }
  }
  gmean[(size_t)g * HD + t] = tot / fmaxf((float)cnt, 1.f);
}

// ---------------- K5: head linear ----------------
__global__ void head_kernel(const float* __restrict__ gmean, const float* __restrict__ y,
                            const float* __restrict__ Wmu, const float* __restrict__ bmu,
                            const float* __restrict__ Wvar, const float* __restrict__ bvar,
                            float* __restrict__ aT) {
  __shared__ float hrow[129];
  const int g = blockIdx.x;
  const int t = threadIdx.x;  // 128
  hrow[t] = gmean[(size_t)g * HD + t];
  if (t == 0) hrow[128] = y[g];
  __syncthreads();
  const int head = t >> 6, n = t & 63;
  const float* __restrict__ W = head ? Wvar : Wmu;
  float acc = head ? bvar[n] : bmu[n];
  for (int k = 0; k < 129; ++k) acc = fmaf(hrow[k], W[k * ZD + n], acc);
  aT[(size_t)(head * ZD + n) * N_GRAPHS + g] = acc;
}

// ---------------- K6: BN stats per feature ----------------
__global__ void bnstats_kernel(const float* __restrict__ aT, float* __restrict__ stats) {
  const int f = blockIdx.x;  // 0..127
  const float* base = aT + (size_t)f * N_GRAPHS;
  float s = 0.f, ss = 0.f;
  for (int i = threadIdx.x; i < N_GRAPHS; i += 256) { float v = base[i]; s += v; ss += v * v; }
#pragma unroll
  for (int off = 1; off < 64; off <<= 1) { s += __shfl_xor(s, off, 64); ss += __shfl_xor(ss, off, 64); }
  __shared__ float ls[8];
  const int wav = threadIdx.x >> 6, lane = threadIdx.x & 63;
  if (lane == 0) { ls[wav * 2] = s; ls[wav * 2 + 1] = ss; }
  __syncthreads();
  if (threadIdx.x == 0) {
    float S = ls[0] + ls[2] + ls[4] + ls[6];
    float SS = ls[1] + ls[3] + ls[5] + ls[7];
    float mean = S / (float)N_GRAPHS;
    float var = SS / (float)N_GRAPHS - mean * mean;
    stats[f * 2] = mean;
    stats[f * 2 + 1] = rsqrtf(var + 1e-5f);
  }
}

// ---------------- K7: BN apply + relu (+sigmoid) ----------------
__global__ void bnapply_kernel(const float* __restrict__ aT, const float* __restrict__ stats,
                               const float* __restrict__ gm, const float* __restrict__ btm,
                               const float* __restrict__ gv, const float* __restrict__ btv,
                               float* __restrict__ out) {
  int t = blockIdx.x * blockDim.x + threadIdx.x;
  if (t >= 2 * N_GRAPHS * ZD) return;
  int head = t >> 18;
  int r = t & (N_GRAPHS * ZD - 1);
  int g = r >> 6, n = r & 63;
  int f = (head << 6) | n;
  float v = aT[(size_t)f * N_GRAPHS + g];
  float z = (v - stats[f * 2]) * stats[f * 2 + 1];
  z = z * (head ? gv[n] : gm[n]) + (head ? btv[n] : btm[n]);
  z = fmaxf(z, 0.f);
  if (head) z = 1.f / (1.f + __expf(-z));
  out[t] = z;
}

extern "C" void kernel_launch(void* const* d_in, const int* in_sizes, int n_in,
                              void* d_out, int out_size, void* d_ws, size_t ws_size,
                              hipStream_t stream) {
  const float* x      = (const float*)d_in[0];
  const int*   ei     = (const int*)d_in[1];
  const float* ew     = (const float*)d_in[2];
  const float* y      = (const float*)d_in[3];
  const int*   batch  = (const int*)d_in[4];
  const float* Wself  = (const float*)d_in[5];
  const float* Wnbr   = (const float*)d_in[6];
  const float* bemb   = (const float*)d_in[7];
  const float* Wmu    = (const float*)d_in[8];
  const float* bmu    = (const float*)d_in[9];
  const float* gmu    = (const float*)d_in[10];
  const float* betamu = (const float*)d_in[11];
  const float* Wvar   = (const float*)d_in[12];
  const float* bvar   = (const float*)d_in[13];
  const float* gvar   = (const float*)d_in[14];
  const float* betavar= (const float*)d_in[15];

  float* ws       = (float*)d_ws;
  int*   cursors  = (int*)(ws + OFF_CUR);
  float* sums     = ws + OFF_SUMS;
  uint2* buf      = (uint2*)(ws + OFF_BUF);
  float* aT       = ws + OFF_AT;
  float* stats    = ws + OFF_STATS;
  uint32_t* wt    = (uint32_t*)(ws + OFF_WT);
  float* gmean    = ws + OFF_GMEAN;
  float* partials = ws + OFF_PART;
  uint32_t* U     = (uint32_t*)(ws + OFF_U);
  uint32_t* V     = (uint32_t*)(ws + OFF_V);

  // zero cursors + sums (fallback) each call
  hipMemsetAsync(ws, 0, (8192ull + 524288ull) * 4ull, stream);

  wprep_kernel<<<2, 256, 0, stream>>>(Wnbr, Wself, wt);
  bucket_build<<<(N_EDGES + 255) / 256, 256, 0, stream>>>(ei, ew, cursors, buf);
  gemm1_uv<<<NBUCKETS, 512, 0, stream>>>(x, wt, bemb, U, V);
  msg_pool<<<NBUCKETS, 512, 0, stream>>>(U, V, buf, cursors, batch, partials, sums);
  reduce_mean<<<N_GRAPHS, 128, 0, stream>>>(partials, sums, batch, gmean);
  head_kernel<<<N_GRAPHS, 128, 0, stream>>>(gmean, y, Wmu, bmu, Wvar, bvar, aT);
  bnstats_kernel<<<128, 256, 0, stream>>>(aT, stats);
  bnapply_kernel<<<(2 * N_GRAPHS * ZD + 255) / 256, 256, 0, stream>>>(
      aT, stats, gmu, betamu, gvar, betavar, (float*)d_out);
}